// Round 9
// baseline (216.790 us; speedup 1.0000x reference)
//
#include <hip/hip_runtime.h>
#include <stdint.h>

// Fused MHA: out = softmax_causal((xq Wq^T)(xk Wk^T)^T / 8) (xv Wv^T) Wo^T
// B=4 S=2048 E=1024 H=16 D=64.
// Workspace layout:
//   [0,16)  AO (attn output, bf16)
//   [48,50) Wqb [50,52) Wkb [52,54) Wvb [54,56) Wob
//   [56,72) Qp  [72,88) Kp  [88,104) Vt (per-head transposed V [b,h,d,s],
//           s-columns INTERLEAVED within each 32-block: pos(s) = (s&3) +
//           4*((s>>4)&1) + 8*((s>>2)&3) + 32*(s>>5))
// QKV projections: 3 SEPARATE dispatches (round-8 PM: fusing them thrashed
// per-XCD L2 -- no data is shared across Q/K/V), fp32 A cast fused into
// staging, T3-minimal double-buffered prefetch (stage k+1 before compute k).

#define LOG2E 1.44269504088896340736f

typedef __bf16 bf16;
typedef __attribute__((ext_vector_type(8))) __bf16 bf16x8;
typedef __attribute__((ext_vector_type(4))) __bf16 bf16x4;
typedef __attribute__((ext_vector_type(4))) float f32x4;

static constexpr int Sq = 2048, Eq = 1024;

__device__ __forceinline__ f32x4 mfma16(bf16x8 a, bf16x8 b, f32x4 c) {
  return __builtin_amdgcn_mfma_f32_16x16x32_bf16(a, b, c, 0, 0, 0);
}

// bare v_exp_f32 (2^x); args bounded, masked -1e30 underflows to 0.
__device__ __forceinline__ float fexp2(float x) {
  return __builtin_amdgcn_exp2f(x);
}

__device__ __forceinline__ void gload16(const bf16* g, bf16* l) {
  __builtin_amdgcn_global_load_lds(
      (const __attribute__((address_space(1))) void*)g,
      (__attribute__((address_space(3))) void*)l, 16, 0, 0);
}

__device__ __forceinline__ bf16x8 scale8(bf16x8 v, float s) {
  bf16x8 o;
#pragma unroll
  for (int i = 0; i < 8; ++i) o[i] = (bf16)((float)v[i] * s);
  return o;
}

__device__ __forceinline__ void store4(bf16* p, f32x4 a, float s) {
  bf16x4 v;
#pragma unroll
  for (int rg = 0; rg < 4; ++rg) v[rg] = (bf16)(a[rg] * s);
  *(bf16x4*)p = v;
}

__device__ __forceinline__ bf16x8 cvt8(const float4& a, const float4& b) {
  bf16x8 v;
  v[0] = (bf16)a.x; v[1] = (bf16)a.y; v[2] = (bf16)a.z; v[3] = (bf16)a.w;
  v[4] = (bf16)b.x; v[5] = (bf16)b.y; v[6] = (bf16)b.z; v[7] = (bf16)b.w;
  return v;
}

// ---------------- weight cast fp32 -> bf16 (4 tensors, 2^17 x8 each) ------
__global__ void cast_w4(const float* __restrict__ a, const float* __restrict__ b,
                        const float* __restrict__ c, const float* __restrict__ d,
                        bf16* __restrict__ oa, bf16* __restrict__ ob,
                        bf16* __restrict__ oc, bf16* __restrict__ od) {
  int i = blockIdx.x * blockDim.x + threadIdx.x;
  int sel = i >> 17, off = i & ((1 << 17) - 1);
  const float* src = sel == 0 ? a : sel == 1 ? b : sel == 2 ? c : d;
  bf16* dst = sel == 0 ? oa : sel == 1 ? ob : sel == 2 ? oc : od;
  const float4* p = (const float4*)src;
  ((bf16x8*)dst)[off] = cvt8(p[off * 2], p[off * 2 + 1]);
}

// ---------------- QKV projection GEMM: C = A_f32 * W_bf16^T ---------------
// 128x128 tile, BK=64, 4 waves, wave owns 64x64. DOUBLE-BUFFERED:
// stage(k+1) issued BEFORE compute(k); A (fp32, cast fused) via
// flat-load->regs, ds_write AFTER compute (vmcnt leaves B's gload_lds in
// flight); B via global_load_lds w=16, linear LDS.
// MODE 0: row-major bf16.  MODE 1: Vt transposed + interleaved columns.
template <int MODE>
__global__ __launch_bounds__(256) void gemm_af32(const float* __restrict__ Af,
                                                 const bf16* __restrict__ W,
                                                 bf16* __restrict__ C) {
  __shared__ __align__(16) bf16 Alds[2][128 * 64];
  __shared__ __align__(16) bf16 Blds[2][128 * 64];

  int bid = blockIdx.x;
  int wg = (bid & 7) * 64 + (bid >> 3);  // XCD swizzle (512 blocks)
  int tm = wg >> 3, tn = wg & 7;         // 64 x 8 tiles
  int tid = threadIdx.x;
  int l = tid & 63, wv = tid >> 6;
  int wm = wv >> 1, wn = wv & 1;
  int l15 = l & 15, lg = l >> 4;

  f32x4 acc[4][4] = {};
  const size_t arow = (size_t)tm * 128, brow = (size_t)tn * 128;
  const int arow_t = tid >> 3;           // + j*32
  const int acol_t = (tid & 7) * 8;

  float4 a0[4], a1[4];

#define ISSUEA(k0_)                                                          \
  _Pragma("unroll") for (int j = 0; j < 4; ++j) {                            \
    const float4* ap =                                                       \
        (const float4*)(Af + (arow + arow_t + j * 32) * 1024 + (k0_) + acol_t); \
    a0[j] = ap[0]; a1[j] = ap[1];                                            \
  }
#define WRITEA(bufp)                                                         \
  _Pragma("unroll") for (int j = 0; j < 4; ++j) {                            \
    *(bf16x8*)(Alds[bufp] + (arow_t + j * 32) * 64 + acol_t) =               \
        cvt8(a0[j], a1[j]);                                                  \
  }
#define ISSUEB(k0_, bufp)                                                    \
  _Pragma("unroll") for (int j = 0; j < 4; ++j) {                            \
    int loc = tid * 16 + j * 4096;                                           \
    int r = loc >> 7;                                                        \
    int c = (loc & 127) >> 1;                                                \
    gload16(W + (brow + r) * 1024 + (k0_) + c,                               \
            (bf16*)((char*)Blds[bufp] + loc));                               \
  }

  // prologue: fill buffer 0
  ISSUEA(0);
  ISSUEB(0, 0);
  WRITEA(0);
  __syncthreads();

  int cur = 0;
  for (int step = 0; step < 16; ++step) {
    if (step < 15) {
      int k1 = (step + 1) * 64;
      ISSUEA(k1);           // A flat loads issued FIRST (drained by WRITEA)
      ISSUEB(k1, cur ^ 1);  // B gload_lds stays in flight until barrier
    }
#pragma unroll
    for (int kk = 0; kk < 2; ++kk) {
      bf16x8 af[4], bfr[4];
#pragma unroll
      for (int t = 0; t < 4; ++t) {
        int ma = wm * 64 + t * 16 + l15;
        af[t] = *(const bf16x8*)((const char*)Alds[cur] + ma * 128 + 16 * lg + 64 * kk);
        int nb = wn * 64 + t * 16 + l15;
        bfr[t] = *(const bf16x8*)((const char*)Blds[cur] + nb * 128 + 16 * lg + 64 * kk);
      }
#pragma unroll
      for (int mt = 0; mt < 4; ++mt)
#pragma unroll
        for (int nt = 0; nt < 4; ++nt)
          acc[mt][nt] = mfma16(af[mt], bfr[nt], acc[mt][nt]);
    }
    if (step < 15) WRITEA(cur ^ 1);  // cvt+write after compute (loads landed)
    __syncthreads();
    cur ^= 1;
  }
#undef ISSUEA
#undef WRITEA
#undef ISSUEB

  int mbase = tm * 128 + wm * 64;
  int nbase = tn * 128 + wn * 64;
  if (MODE == 0) {
#pragma unroll
    for (int mt = 0; mt < 4; ++mt)
#pragma unroll
      for (int nt = 0; nt < 4; ++nt) {
        int m0 = mbase + mt * 16 + (lg << 2);
        int n = nbase + nt * 16 + l15;
#pragma unroll
        for (int rg = 0; rg < 4; ++rg)
          C[(size_t)(m0 + rg) * 1024 + n] = (bf16)acc[mt][nt][rg];
      }
  } else {  // Vt[(b*16+h)*64 + d][pos(s)], interleaved columns
#pragma unroll
    for (int mt = 0; mt < 4; ++mt)
#pragma unroll
      for (int nt = 0; nt < 4; ++nt) {
        int m0 = mbase + mt * 16 + (lg << 2);
        int n = nbase + nt * 16 + l15;
        bf16x4 vv;
#pragma unroll
        for (int rg = 0; rg < 4; ++rg) vv[rg] = (bf16)acc[mt][nt][rg];
        int bb = m0 >> 11, s0 = m0 & 2047;
        int sp = (s0 & ~31) | (((s0 >> 4) & 1) << 2) | (((s0 >> 2) & 3) << 3);
        size_t off =
            ((size_t)((bb * 16 + (n >> 6)) * 64 + (n & 63))) * 2048 + sp;
        *(bf16x4*)(C + off) = vv;
      }
  }
}

// ---------------- WO GEMM: C_f32 = A_bf16 * W_bf16^T (m97 pattern) --------
__global__ __launch_bounds__(256) void gemm_wo(const bf16* __restrict__ A,
                                               const bf16* __restrict__ W,
                                               float* __restrict__ Cout) {
  __shared__ __align__(16) bf16 Alds[128 * 64];
  __shared__ __align__(16) bf16 Blds[128 * 64];

  int bid = blockIdx.x;
  int wg = (bid & 7) * 64 + (bid >> 3);
  int tm = wg >> 3, tn = wg & 7;
  int tid = threadIdx.x;
  int l = tid & 63, wv = tid >> 6;
  int wm = wv >> 1, wn = wv & 1;
  int l15 = l & 15, lg = l >> 4;

  f32x4 acc[4][4] = {};
  const size_t arow = (size_t)tm * 128, brow = (size_t)tn * 128;

  for (int k0 = 0; k0 < 1024; k0 += 64) {
#pragma unroll
    for (int j = 0; j < 4; ++j) {
      int loc = tid * 16 + j * 4096;
      int r = loc >> 7;
      int c = (loc & 127) >> 1;
      gload16(W + (brow + r) * 1024 + k0 + c, (bf16*)((char*)Blds + loc));
      gload16(A + (arow + r) * 1024 + k0 + c, (bf16*)((char*)Alds + loc));
    }
    __syncthreads();
#pragma unroll
    for (int kk = 0; kk < 2; ++kk) {
      bf16x8 af[4], bfr[4];
#pragma unroll
      for (int t = 0; t < 4; ++t) {
        int ma = wm * 64 + t * 16 + l15;
        af[t] = *(const bf16x8*)((const char*)Alds + ma * 128 + 16 * lg + 64 * kk);
        int nb = wn * 64 + t * 16 + l15;
        bfr[t] = *(const bf16x8*)((const char*)Blds + nb * 128 + 16 * lg + 64 * kk);
      }
#pragma unroll
      for (int mt = 0; mt < 4; ++mt)
#pragma unroll
        for (int nt = 0; nt < 4; ++nt)
          acc[mt][nt] = mfma16(af[mt], bfr[nt], acc[mt][nt]);
    }
    __syncthreads();
  }

  int mbase = tm * 128 + wm * 64;
  int nbase = tn * 128 + wn * 64;
#pragma unroll
  for (int mt = 0; mt < 4; ++mt)
#pragma unroll
    for (int nt = 0; nt < 4; ++nt) {
      int m0 = mbase + mt * 16 + (lg << 2);
      int n = nbase + nt * 16 + l15;
#pragma unroll
      for (int rg = 0; rg < 4; ++rg)
        Cout[(size_t)(m0 + rg) * 1024 + n] = acc[mt][nt][rg];
    }
}

// ---------------- causal flash attention (uniform blocks) ------------------
// 512 blocks; block = (b,h, q-tile PAIR {j, 15-j}) -> EXACTLY 34 KV chunks
// per block. Two sequential segments share one continuous double-buffered
// KV stage stream. 4 waves lockstep, 64-row KV chunks, global_load_lds w=16
// with XOR-swizzle pre-applied on the global source. Swapped QK^T +
// static-max softmax (C=6 in MFMA C-init), bare v_exp_f32, row-sum via
// mfma(ones,P). V reads single b128 via interleaved Vt layout.
__global__ __launch_bounds__(256) void attn_kernel(
    const bf16* __restrict__ Qp, const bf16* __restrict__ Kp,
    const bf16* __restrict__ Vt, bf16* __restrict__ AO) {
  __shared__ __align__(16) bf16 sm[2][2][4096];  // [buf][K|V][64 x 128B]

  int bid = blockIdx.x;                           // 512
  int bh = ((bid & 7) << 3) | ((bid >> 3) & 7);   // 8 heads per XCD
  int j = bid >> 6;                               // 0..7: tiles j and 15-j
  int b = bh >> 4, h = bh & 15;
  int tid = threadIdx.x;
  int w = tid >> 6, l = tid & 63;
  int l15 = l & 15, lg = l >> 4;

  int ncA = 2 * j + 2, ncB = 32 - 2 * j;          // ncA + ncB = 34
  const float sc = 0.125f * LOG2E;
  bf16 one1 = (bf16)1.0f;
  bf16x8 ones = {one1, one1, one1, one1, one1, one1, one1, one1};

  const bf16* Kbase = Kp + (size_t)(b * 2048) * 1024 + h * 64;
  const bf16* Vbase = Vt + (size_t)(bh * 64) * 2048;

  int qw0 = j * 128 + w * 32;
  int cdiag = 2 * j + (w >> 1);
  int qg0 = qw0 + l15, qg1 = qw0 + 16 + l15;
  const bf16* qp_ = Qp + (size_t)(b * 2048 + qw0 + l15) * 1024 + h * 64 + 8 * lg;
  bf16x8 q00 = scale8(*(const bf16x8*)qp_, sc);
  bf16x8 q01 = scale8(*(const bf16x8*)(qp_ + 32), sc);
  bf16x8 q10 = scale8(*(const bf16x8*)(qp_ + 16384), sc);
  bf16x8 q11 = scale8(*(const bf16x8*)(qp_ + 16384 + 32), sc);

  f32x4 r0 = {0.f, 0.f, 0.f, 0.f}, r1 = r0;
  f32x4 o0[4] = {}, o1[4] = {};

#define STAGE(c_, bufp)                                                     \
  do {                                                                      \
    int _c = (c_);                                                          \
    _Pragma("unroll") for (int jj = 0; jj < 2; ++jj) {                      \
      int loc = tid * 16 + jj * 4096;                                       \
      int row = loc >> 7, u = (loc >> 4) & 7;                               \
      int sel = (u ^ (row & 7)) << 3;                                       \
      gload16(Kbase + (size_t)(_c * 64 + row) * 1024 + sel,                 \
              (bf16*)((char*)sm[bufp][0] + loc));                           \
      gload16(Vbase + (size_t)row * 2048 + _c * 64 + sel,                   \
              (bf16*)((char*)sm[bufp][1] + loc));                           \
    }                                                                       \
  } while (0)

#define CHUNKC(c_)                                                          \
  do {                                                                      \
    const int _c = (c_);                                                    \
    const char* lK = (const char*)sm[cur][0];                               \
    const char* lV = (const char*)sm[cur][1];                               \
    const f32x4 cinit = {-6.f, -6.f, -6.f, -6.f};                           \
    f32x4 s0[4], s1[4];                                                     \
    _Pragma("unroll") for (int kt = 0; kt < 4; ++kt) {                      \
      int row = kt * 16 + l15, sw = (row & 7) << 4;                         \
      const char* kb = lK + row * 128;                                      \
      bf16x8 kf0 = *(const bf16x8*)(kb + ((lg * 16) ^ sw));                 \
      bf16x8 kf1 = *(const bf16x8*)(kb + ((64 + lg * 16) ^ sw));            \
      s0[kt] = mfma16(kf1, q01, mfma16(kf0, q00, cinit));                   \
      s1[kt] = mfma16(kf1, q11, mfma16(kf0, q10, cinit));                   \
    }                                                                       \
    if (_c == cdiag) {                                                      \
      _Pragma("unroll") for (int kt = 0; kt < 4; ++kt)                      \
          _Pragma("unroll") for (int rg = 0; rg < 4; ++rg) {                \
        int kg = _c * 64 + kt * 16 + 4 * lg + rg;                           \
        if (kg > qg0) s0[kt][rg] = -1e30f;                                  \
        if (kg > qg1) s1[kt][rg] = -1e30f;                                  \
      }                                                                     \
    }                                                                       \
    bf16x8 plo0, phi0, plo1, phi1;                                          \
    _Pragma("unroll") for (int rg = 0; rg < 4; ++rg) {                      \
      plo0[rg] = (bf16)fexp2(s0[0][rg]); plo0[rg + 4] = (bf16)fexp2(s0[1][rg]); \
      phi0[rg] = (bf16)fexp2(s0[2][rg]); phi0[rg + 4] = (bf16)fexp2(s0[3][rg]); \
      plo1[rg] = (bf16)fexp2(s1[0][rg]); plo1[rg + 4] = (bf16)fexp2(s1[1][rg]); \
      phi1[rg] = (bf16)fexp2(s1[2][rg]); phi1[rg + 4] = (bf16)fexp2(s1[3][rg]); \
    }                                                                       \
    r0 = mfma16(ones, phi0, mfma16(ones, plo0, r0));                        \
    r1 = mfma16(ones, phi1, mfma16(ones, plo1, r1));                        \
    _Pragma("unroll") for (int dt = 0; dt < 4; ++dt) {                      \
      int row = dt * 16 + l15, sw = (row & 7) << 4;                         \
      const char* vb = lV + row * 128;                                      \
      bf16x8 vf0 = *(const bf16x8*)(vb + ((lg * 16) ^ sw));                 \
      bf16x8 vf1 = *(const bf16x8*)(vb + ((64 + lg * 16) ^ sw));            \
      o0[dt] = mfma16(vf1, phi0, mfma16(vf0, plo0, o0[dt]));                \
      o1[dt] = mfma16(vf1, phi1, mfma16(vf0, plo1, o1[dt]));                \
    }                                                                       \
  } while (0)

#define STOREOUT()                                                          \
  do {                                                                      \
    float inv0 = 1.0f / r0[0], inv1 = 1.0f / r1[0];                         \
    bf16* ob = AO + (size_t)(b * 2048 + qw0 + l15) * 1024 + h * 64 + 4 * lg; \
    _Pragma("unroll") for (int dt = 0; dt < 4; ++dt) {                      \
      store4(ob + dt * 16, o0[dt], inv0);                                   \
      store4(ob + 16384 + dt * 16, o1[dt], inv1);                           \
    }                                                                       \
  } while (0)

  STAGE(0, 0);
  __syncthreads();
  int cur = 0;

  // segment A: q-tile j, KV chunks 0..ncA-1
  for (int c = 0; c < ncA; ++c) {
    int g = c + 1;
    STAGE(g < ncA ? g : g - ncA, cur ^ 1);  // last A stage = B chunk 0
    if (c <= cdiag) CHUNKC(c);
    __syncthreads();
    cur ^= 1;
  }
  STOREOUT();

  // switch to q-tile 15-j
  qw0 = (15 - j) * 128 + w * 32;
  cdiag = 2 * (15 - j) + (w >> 1);
  qg0 = qw0 + l15; qg1 = qw0 + 16 + l15;
  qp_ = Qp + (size_t)(b * 2048 + qw0 + l15) * 1024 + h * 64 + 8 * lg;
  q00 = scale8(*(const bf16x8*)qp_, sc);
  q01 = scale8(*(const bf16x8*)(qp_ + 32), sc);
  q10 = scale8(*(const bf16x8*)(qp_ + 16384), sc);
  q11 = scale8(*(const bf16x8*)(qp_ + 16384 + 32), sc);
  r0 = f32x4{0.f, 0.f, 0.f, 0.f}; r1 = r0;
#pragma unroll
  for (int dt = 0; dt < 4; ++dt) { o0[dt] = r0; o1[dt] = r0; }

  // segment B: q-tile 15-j, KV chunks 0..ncB-1 (stream continues)
  for (int c = 0; c < ncB; ++c) {
    if (c + 1 < ncB) STAGE(c + 1, cur ^ 1);
    if (c <= cdiag) CHUNKC(c);
    __syncthreads();
    cur ^= 1;
  }
  STOREOUT();
#undef STAGE
#undef CHUNKC
#undef STOREOUT
}

extern "C" void kernel_launch(void* const* d_in, const int* in_sizes, int n_in,
                              void* d_out, int out_size, void* d_ws, size_t ws_size,
                              hipStream_t stream) {
  (void)in_sizes; (void)n_in; (void)out_size; (void)ws_size;
  const float* dq = (const float*)d_in[0];
  const float* dk = (const float*)d_in[1];
  const float* dv = (const float*)d_in[2];
  const float* wq = (const float*)d_in[3];
  const float* wk = (const float*)d_in[4];
  const float* wv = (const float*)d_in[5];
  const float* wo = (const float*)d_in[6];

  char* ws = (char*)d_ws;
  const size_t MB = 1u << 20;
  bf16* AO  = (bf16*)(ws + 0 * MB);
  bf16* wqb = (bf16*)(ws + 48 * MB);
  bf16* wkb = (bf16*)(ws + 50 * MB);
  bf16* wvb = (bf16*)(ws + 52 * MB);
  bf16* wob = (bf16*)(ws + 54 * MB);
  bf16* Qp  = (bf16*)(ws + 56 * MB);
  bf16* Kp  = (bf16*)(ws + 72 * MB);
  bf16* Vt  = (bf16*)(ws + 88 * MB);

  cast_w4<<<4 * 512, 256, 0, stream>>>(wq, wk, wv, wo, wqb, wkb, wvb, wob);
  gemm_af32<0><<<512, 256, 0, stream>>>(dq, wqb, Qp);
  gemm_af32<0><<<512, 256, 0, stream>>>(dk, wkb, Kp);
  gemm_af32<1><<<512, 256, 0, stream>>>(dv, wvb, Vt);
  attn_kernel<<<512, 256, 0, stream>>>(Qp, Kp, Vt, AO);
  gemm_wo<<<512, 256, 0, stream>>>(AO, wob, (float*)d_out);
}

// Round 10
// 190.671 us; speedup vs baseline: 1.1370x; 1.1370x over previous
//
#include <hip/hip_runtime.h>
#include <stdint.h>

// Fused MHA: out = softmax_causal((xq Wq^T)(xk Wk^T)^T / 8) (xv Wv^T) Wo^T
// B=4 S=2048 E=1024 H=16 D=64.
// Workspace layout:
//   [0,16)  AO (attn output, bf16)
//   [48,50) Wqb [50,52) Wkb [52,54) Wvb [54,56) Wob
//   [56,72) Qp  [72,88) Kp  [88,104) Vt (per-head transposed V [b,h,d,s],
//           s-columns INTERLEAVED within each 32-block: pos(s) = (s&3) +
//           4*((s>>4)&1) + 8*((s>>2)&3) + 32*(s>>5))
// QKV projections: 3 separate 1-phase dispatches (round-9 PM: dbuf variant
// regressed; this is the measured-good round-7 kernel). Attn: depth-2
// counted-vmcnt pipeline (T4) -- inputs are L2-cold after the projection
// GEMMs stream ~150MB, so HBM latency must be hidden across barriers.

#define LOG2E 1.44269504088896340736f

typedef __bf16 bf16;
typedef __attribute__((ext_vector_type(8))) __bf16 bf16x8;
typedef __attribute__((ext_vector_type(4))) __bf16 bf16x4;
typedef __attribute__((ext_vector_type(4))) float f32x4;

static constexpr int Sq = 2048, Eq = 1024;

__device__ __forceinline__ f32x4 mfma16(bf16x8 a, bf16x8 b, f32x4 c) {
  return __builtin_amdgcn_mfma_f32_16x16x32_bf16(a, b, c, 0, 0, 0);
}

// bare v_exp_f32 (2^x); args bounded, masked -1e30 underflows to 0.
__device__ __forceinline__ float fexp2(float x) {
  return __builtin_amdgcn_exp2f(x);
}

__device__ __forceinline__ void gload16(const bf16* g, bf16* l) {
  __builtin_amdgcn_global_load_lds(
      (const __attribute__((address_space(1))) void*)g,
      (__attribute__((address_space(3))) void*)l, 16, 0, 0);
}

__device__ __forceinline__ bf16x8 scale8(bf16x8 v, float s) {
  bf16x8 o;
#pragma unroll
  for (int i = 0; i < 8; ++i) o[i] = (bf16)((float)v[i] * s);
  return o;
}

__device__ __forceinline__ void store4(bf16* p, f32x4 a, float s) {
  bf16x4 v;
#pragma unroll
  for (int rg = 0; rg < 4; ++rg) v[rg] = (bf16)(a[rg] * s);
  *(bf16x4*)p = v;
}

__device__ __forceinline__ bf16x8 cvt8(const float4& a, const float4& b) {
  bf16x8 v;
  v[0] = (bf16)a.x; v[1] = (bf16)a.y; v[2] = (bf16)a.z; v[3] = (bf16)a.w;
  v[4] = (bf16)b.x; v[5] = (bf16)b.y; v[6] = (bf16)b.z; v[7] = (bf16)b.w;
  return v;
}

// ---------------- weight cast fp32 -> bf16 (4 tensors, 2^17 x8 each) ------
__global__ void cast_w4(const float* __restrict__ a, const float* __restrict__ b,
                        const float* __restrict__ c, const float* __restrict__ d,
                        bf16* __restrict__ oa, bf16* __restrict__ ob,
                        bf16* __restrict__ oc, bf16* __restrict__ od) {
  int i = blockIdx.x * blockDim.x + threadIdx.x;
  int sel = i >> 17, off = i & ((1 << 17) - 1);
  const float* src = sel == 0 ? a : sel == 1 ? b : sel == 2 ? c : d;
  bf16* dst = sel == 0 ? oa : sel == 1 ? ob : sel == 2 ? oc : od;
  const float4* p = (const float4*)src;
  ((bf16x8*)dst)[off] = cvt8(p[off * 2], p[off * 2 + 1]);
}

// ---------------- QKV projection GEMM (round-7 measured-good 1-phase) -----
// C = A_f32 * W_bf16^T. 128x128 tile, BK=64, 4 waves. A fp32 cast fused
// into staging (float4->cvt->ds_write); B via global_load_lds w=16.
// MODE 0: row-major bf16.  MODE 1: Vt transposed + interleaved columns.
template <int MODE>
__global__ __launch_bounds__(256) void gemm_proj(const float* __restrict__ Af,
                                                 const bf16* __restrict__ W,
                                                 bf16* __restrict__ C) {
  __shared__ __align__(16) bf16 Alds[128 * 64];
  __shared__ __align__(16) bf16 Blds[128 * 64];

  int bid = blockIdx.x;
  int wg = (bid & 7) * 64 + (bid >> 3);  // XCD swizzle (512 blocks)
  int tm = wg >> 3, tn = wg & 7;         // 64 x 8 tiles
  int tid = threadIdx.x;
  int l = tid & 63, wv = tid >> 6;
  int wm = wv >> 1, wn = wv & 1;
  int l15 = l & 15, lg = l >> 4;

  f32x4 acc[4][4] = {};
  const size_t arow = (size_t)tm * 128, brow = (size_t)tn * 128;

  for (int k0 = 0; k0 < 1024; k0 += 64) {
#pragma unroll
    for (int j = 0; j < 4; ++j) {
      int loc = tid * 16 + j * 4096;
      int r = loc >> 7;
      int c = (loc & 127) >> 1;
      gload16(W + (brow + r) * 1024 + k0 + c, (bf16*)((char*)Blds + loc));
    }
#pragma unroll
    for (int j = 0; j < 4; ++j) {
      int row = (tid >> 3) + j * 32;
      int colf = (tid & 7) * 8;
      const float4* ap = (const float4*)(Af + (arow + row) * 1024 + k0 + colf);
      float4 a0 = ap[0], a1 = ap[1];
      *(bf16x8*)(Alds + row * 64 + colf) = cvt8(a0, a1);
    }
    __syncthreads();
#pragma unroll
    for (int kk = 0; kk < 2; ++kk) {
      bf16x8 af[4], bfr[4];
#pragma unroll
      for (int t = 0; t < 4; ++t) {
        int ma = wm * 64 + t * 16 + l15;
        af[t] = *(const bf16x8*)((const char*)Alds + ma * 128 + 16 * lg + 64 * kk);
        int nb = wn * 64 + t * 16 + l15;
        bfr[t] = *(const bf16x8*)((const char*)Blds + nb * 128 + 16 * lg + 64 * kk);
      }
#pragma unroll
      for (int mt = 0; mt < 4; ++mt)
#pragma unroll
        for (int nt = 0; nt < 4; ++nt)
          acc[mt][nt] = mfma16(af[mt], bfr[nt], acc[mt][nt]);
    }
    __syncthreads();
  }

  int mbase = tm * 128 + wm * 64;
  int nbase = tn * 128 + wn * 64;
  if (MODE == 0) {
#pragma unroll
    for (int mt = 0; mt < 4; ++mt)
#pragma unroll
      for (int nt = 0; nt < 4; ++nt) {
        int m0 = mbase + mt * 16 + (lg << 2);
        int n = nbase + nt * 16 + l15;
#pragma unroll
        for (int rg = 0; rg < 4; ++rg)
          C[(size_t)(m0 + rg) * 1024 + n] = (bf16)acc[mt][nt][rg];
      }
  } else {  // Vt[(b*16+h)*64 + d][pos(s)], interleaved columns
#pragma unroll
    for (int mt = 0; mt < 4; ++mt)
#pragma unroll
      for (int nt = 0; nt < 4; ++nt) {
        int m0 = mbase + mt * 16 + (lg << 2);
        int n = nbase + nt * 16 + l15;
        bf16x4 vv;
#pragma unroll
        for (int rg = 0; rg < 4; ++rg) vv[rg] = (bf16)acc[mt][nt][rg];
        int bb = m0 >> 11, s0 = m0 & 2047;
        int sp = (s0 & ~31) | (((s0 >> 4) & 1) << 2) | (((s0 >> 2) & 3) << 3);
        size_t off =
            ((size_t)((bb * 16 + (n >> 6)) * 64 + (n & 63))) * 2048 + sp;
        *(bf16x4*)(C + off) = vv;
      }
  }
}

// ---------------- WO GEMM: C_f32 = A_bf16 * W_bf16^T (m97 pattern) --------
__global__ __launch_bounds__(256) void gemm_wo(const bf16* __restrict__ A,
                                               const bf16* __restrict__ W,
                                               float* __restrict__ Cout) {
  __shared__ __align__(16) bf16 Alds[128 * 64];
  __shared__ __align__(16) bf16 Blds[128 * 64];

  int bid = blockIdx.x;
  int wg = (bid & 7) * 64 + (bid >> 3);
  int tm = wg >> 3, tn = wg & 7;
  int tid = threadIdx.x;
  int l = tid & 63, wv = tid >> 6;
  int wm = wv >> 1, wn = wv & 1;
  int l15 = l & 15, lg = l >> 4;

  f32x4 acc[4][4] = {};
  const size_t arow = (size_t)tm * 128, brow = (size_t)tn * 128;

  for (int k0 = 0; k0 < 1024; k0 += 64) {
#pragma unroll
    for (int j = 0; j < 4; ++j) {
      int loc = tid * 16 + j * 4096;
      int r = loc >> 7;
      int c = (loc & 127) >> 1;
      gload16(W + (brow + r) * 1024 + k0 + c, (bf16*)((char*)Blds + loc));
      gload16(A + (arow + r) * 1024 + k0 + c, (bf16*)((char*)Alds + loc));
    }
    __syncthreads();
#pragma unroll
    for (int kk = 0; kk < 2; ++kk) {
      bf16x8 af[4], bfr[4];
#pragma unroll
      for (int t = 0; t < 4; ++t) {
        int ma = wm * 64 + t * 16 + l15;
        af[t] = *(const bf16x8*)((const char*)Alds + ma * 128 + 16 * lg + 64 * kk);
        int nb = wn * 64 + t * 16 + l15;
        bfr[t] = *(const bf16x8*)((const char*)Blds + nb * 128 + 16 * lg + 64 * kk);
      }
#pragma unroll
      for (int mt = 0; mt < 4; ++mt)
#pragma unroll
        for (int nt = 0; nt < 4; ++nt)
          acc[mt][nt] = mfma16(af[mt], bfr[nt], acc[mt][nt]);
    }
    __syncthreads();
  }

  int mbase = tm * 128 + wm * 64;
  int nbase = tn * 128 + wn * 64;
#pragma unroll
  for (int mt = 0; mt < 4; ++mt)
#pragma unroll
    for (int nt = 0; nt < 4; ++nt) {
      int m0 = mbase + mt * 16 + (lg << 2);
      int n = nbase + nt * 16 + l15;
#pragma unroll
      for (int rg = 0; rg < 4; ++rg)
        Cout[(size_t)(m0 + rg) * 1024 + n] = acc[mt][nt][rg];
    }
}

// ---------------- causal flash attention (depth-2 counted-vmcnt) ----------
// 512 blocks; block = (b,h, q-tile PAIR {j, 15-j}) -> exactly 34 KV chunks.
// 3 LDS buffers; stage chunk g+2 each iter; ONE fused
// "s_waitcnt vmcnt(4); s_barrier" per chunk (T4): each wave waits only its
// own 4 gload_lds for chunk g, leaving 8 loads in flight across the
// barrier. vmcnt(0) only on the last chunk. Swapped QK^T + static-max
// softmax (C=6 in MFMA C-init), bare v_exp_f32, row-sum via mfma(ones,P).
// V reads single b128 via interleaved Vt layout (conflicts = 0, round 9).
__global__ __launch_bounds__(256) void attn_kernel(
    const bf16* __restrict__ Qp, const bf16* __restrict__ Kp,
    const bf16* __restrict__ Vt, bf16* __restrict__ AO) {
  __shared__ __align__(16) bf16 sm[3][2][4096];  // [buf][K|V][64 x 128B]

  int bid = blockIdx.x;                           // 512
  int bh = ((bid & 7) << 3) | ((bid >> 3) & 7);   // 8 heads per XCD
  int j = bid >> 6;                               // 0..7: tiles j and 15-j
  int b = bh >> 4, h = bh & 15;
  int tid = threadIdx.x;
  int w = tid >> 6, l = tid & 63;
  int l15 = l & 15, lg = l >> 4;

  const int ncA = 2 * j + 2;                      // chunks for tile j
  const int NC = 34;                              // total staged chunks
  const float sc = 0.125f * LOG2E;
  bf16 one1 = (bf16)1.0f;
  bf16x8 ones = {one1, one1, one1, one1, one1, one1, one1, one1};

  const bf16* Kbase = Kp + (size_t)(b * 2048) * 1024 + h * 64;
  const bf16* Vbase = Vt + (size_t)(bh * 64) * 2048;

  // segment-mutable Q state (tile j first)
  int qw0 = j * 128 + w * 32;
  int cdiag = 2 * j + (w >> 1);
  int qg0 = qw0 + l15, qg1 = qw0 + 16 + l15;
  const bf16* qp_ = Qp + (size_t)(b * 2048 + qw0 + l15) * 1024 + h * 64 + 8 * lg;
  bf16x8 q00 = scale8(*(const bf16x8*)qp_, sc);
  bf16x8 q01 = scale8(*(const bf16x8*)(qp_ + 32), sc);
  bf16x8 q10 = scale8(*(const bf16x8*)(qp_ + 16384), sc);
  bf16x8 q11 = scale8(*(const bf16x8*)(qp_ + 16384 + 32), sc);

  f32x4 r0 = {0.f, 0.f, 0.f, 0.f}, r1 = r0;
  f32x4 o0[4] = {}, o1[4] = {};

#define STAGE(c_, bufp)                                                     \
  do {                                                                      \
    int _c = (c_);                                                          \
    _Pragma("unroll") for (int jj = 0; jj < 2; ++jj) {                      \
      int loc = tid * 16 + jj * 4096;                                       \
      int row = loc >> 7, u = (loc >> 4) & 7;                               \
      int sel = (u ^ (row & 7)) << 3;                                       \
      gload16(Kbase + (size_t)(_c * 64 + row) * 1024 + sel,                 \
              (bf16*)((char*)sm[bufp][0] + loc));                           \
      gload16(Vbase + (size_t)row * 2048 + _c * 64 + sel,                   \
              (bf16*)((char*)sm[bufp][1] + loc));                           \
    }                                                                       \
  } while (0)

#define CHUNKC(c_, bufc_)                                                   \
  do {                                                                      \
    const int _c = (c_);                                                    \
    const char* lK = (const char*)sm[bufc_][0];                             \
    const char* lV = (const char*)sm[bufc_][1];                             \
    const f32x4 cinit = {-6.f, -6.f, -6.f, -6.f};                           \
    f32x4 s0[4], s1[4];                                                     \
    _Pragma("unroll") for (int kt = 0; kt < 4; ++kt) {                      \
      int row = kt * 16 + l15, sw = (row & 7) << 4;                         \
      const char* kb = lK + row * 128;                                      \
      bf16x8 kf0 = *(const bf16x8*)(kb + ((lg * 16) ^ sw));                 \
      bf16x8 kf1 = *(const bf16x8*)(kb + ((64 + lg * 16) ^ sw));            \
      s0[kt] = mfma16(kf1, q01, mfma16(kf0, q00, cinit));                   \
      s1[kt] = mfma16(kf1, q11, mfma16(kf0, q10, cinit));                   \
    }                                                                       \
    if (_c == cdiag) {                                                      \
      _Pragma("unroll") for (int kt = 0; kt < 4; ++kt)                      \
          _Pragma("unroll") for (int rg = 0; rg < 4; ++rg) {                \
        int kg = _c * 64 + kt * 16 + 4 * lg + rg;                           \
        if (kg > qg0) s0[kt][rg] = -1e30f;                                  \
        if (kg > qg1) s1[kt][rg] = -1e30f;                                  \
      }                                                                     \
    }                                                                       \
    bf16x8 plo0, phi0, plo1, phi1;                                          \
    _Pragma("unroll") for (int rg = 0; rg < 4; ++rg) {                      \
      plo0[rg] = (bf16)fexp2(s0[0][rg]); plo0[rg + 4] = (bf16)fexp2(s0[1][rg]); \
      phi0[rg] = (bf16)fexp2(s0[2][rg]); phi0[rg + 4] = (bf16)fexp2(s0[3][rg]); \
      plo1[rg] = (bf16)fexp2(s1[0][rg]); plo1[rg + 4] = (bf16)fexp2(s1[1][rg]); \
      phi1[rg] = (bf16)fexp2(s1[2][rg]); phi1[rg + 4] = (bf16)fexp2(s1[3][rg]); \
    }                                                                       \
    r0 = mfma16(ones, phi0, mfma16(ones, plo0, r0));                        \
    r1 = mfma16(ones, phi1, mfma16(ones, plo1, r1));                        \
    _Pragma("unroll") for (int dt = 0; dt < 4; ++dt) {                      \
      int row = dt * 16 + l15, sw = (row & 7) << 4;                         \
      const char* vb = lV + row * 128;                                      \
      bf16x8 vf0 = *(const bf16x8*)(vb + ((lg * 16) ^ sw));                 \
      bf16x8 vf1 = *(const bf16x8*)(vb + ((64 + lg * 16) ^ sw));            \
      o0[dt] = mfma16(vf1, phi0, mfma16(vf0, plo0, o0[dt]));                \
      o1[dt] = mfma16(vf1, phi1, mfma16(vf0, plo1, o1[dt]));                \
    }                                                                       \
  } while (0)

#define STOREOUT()                                                          \
  do {                                                                      \
    float inv0 = 1.0f / r0[0], inv1 = 1.0f / r1[0];                         \
    bf16* ob = AO + (size_t)(b * 2048 + qw0 + l15) * 1024 + h * 64 + 4 * lg; \
    _Pragma("unroll") for (int dt = 0; dt < 4; ++dt) {                      \
      store4(ob + dt * 16, o0[dt], inv0);                                   \
      store4(ob + 16384 + dt * 16, o1[dt], inv1);                           \
    }                                                                       \
  } while (0)

  // prologue: chunks 0 and 1 in flight (kvof(1)=1 since ncA>=2)
  STAGE(0, 0);
  STAGE(1, 1);

  for (int g = 0; g < NC; ++g) {
    // wait chunk g's 4 gload_lds (in-order retirement), leave rest in
    // flight; barrier publishes all waves' chunk-g data. Fused in ONE asm
    // so no LDS op can slip between the wait and the barrier.
    if (g < NC - 1)
      asm volatile("s_waitcnt vmcnt(4)\n\ts_barrier" ::: "memory");
    else
      asm volatile("s_waitcnt vmcnt(0)\n\ts_barrier" ::: "memory");

    if (g + 2 < NC) {
      int gn = g + 2;
      int cn = gn < ncA ? gn : gn - ncA;
      STAGE(cn, gn % 3);  // overwrites buf (g-1)%3: read finished last iter
    }

    if (g == ncA) {  // segment switch: store tile-j output, load tile 15-j
      STOREOUT();
      qw0 = (15 - j) * 128 + w * 32;
      cdiag = 2 * (15 - j) + (w >> 1);
      qg0 = qw0 + l15; qg1 = qw0 + 16 + l15;
      qp_ = Qp + (size_t)(b * 2048 + qw0 + l15) * 1024 + h * 64 + 8 * lg;
      q00 = scale8(*(const bf16x8*)qp_, sc);
      q01 = scale8(*(const bf16x8*)(qp_ + 32), sc);
      q10 = scale8(*(const bf16x8*)(qp_ + 16384), sc);
      q11 = scale8(*(const bf16x8*)(qp_ + 16384 + 32), sc);
      r0 = f32x4{0.f, 0.f, 0.f, 0.f}; r1 = r0;
#pragma unroll
      for (int dt = 0; dt < 4; ++dt) { o0[dt] = r0; o1[dt] = r0; }
    }

    int c = g < ncA ? g : g - ncA;
    if (c <= cdiag) CHUNKC(c, g % 3);
  }
  STOREOUT();
#undef STAGE
#undef CHUNKC
#undef STOREOUT
}

extern "C" void kernel_launch(void* const* d_in, const int* in_sizes, int n_in,
                              void* d_out, int out_size, void* d_ws, size_t ws_size,
                              hipStream_t stream) {
  (void)in_sizes; (void)n_in; (void)out_size; (void)ws_size;
  const float* dq = (const float*)d_in[0];
  const float* dk = (const float*)d_in[1];
  const float* dv = (const float*)d_in[2];
  const float* wq = (const float*)d_in[3];
  const float* wk = (const float*)d_in[4];
  const float* wv = (const float*)d_in[5];
  const float* wo = (const float*)d_in[6];

  char* ws = (char*)d_ws;
  const size_t MB = 1u << 20;
  bf16* AO  = (bf16*)(ws + 0 * MB);
  bf16* wqb = (bf16*)(ws + 48 * MB);
  bf16* wkb = (bf16*)(ws + 50 * MB);
  bf16* wvb = (bf16*)(ws + 52 * MB);
  bf16* wob = (bf16*)(ws + 54 * MB);
  bf16* Qp  = (bf16*)(ws + 56 * MB);
  bf16* Kp  = (bf16*)(ws + 72 * MB);
  bf16* Vt  = (bf16*)(ws + 88 * MB);

  cast_w4<<<4 * 512, 256, 0, stream>>>(wq, wk, wv, wo, wqb, wkb, wvb, wob);
  gemm_proj<0><<<512, 256, 0, stream>>>(dq, wqb, Qp);
  gemm_proj<0><<<512, 256, 0, stream>>>(dk, wkb, Kp);
  gemm_proj<1><<<512, 256, 0, stream>>>(dv, wvb, Vt);
  attn_kernel<<<512, 256, 0, stream>>>(Qp, Kp, Vt, AO);
  gemm_wo<<<512, 256, 0, stream>>>(AO, wob, (float*)d_out);
}